// Round 7
// baseline (154.121 us; speedup 1.0000x reference)
//
#include <hip/hip_runtime.h>
#include <hip/hip_bf16.h>
#include <cstdint>
#include <cstddef>

#define BB   64
#define CINN 64
#define TS   4096
#define FF   128
#define KS   64
#define TOUT (TS - KS + 1)   // 4033
#define TTF  256             // outputs per fused block
#define RT   336             // t-range staged (outputs + 80 halo for K-band reads)
#define SXT  37              // xT row stride (dwords) — R4-validated conflict pattern
#define YSTR 220             // ych row stride (dwords): mult-of-4 (b128 align), 4q*220%32=16 -> 2-way free

typedef __attribute__((ext_vector_type(8))) short short8;
typedef __attribute__((ext_vector_type(4))) float f32x4;
union FragU { unsigned int u[4]; short8 v; uint4 q4; };

static __device__ __forceinline__ unsigned int f2bf_u(float f) {
    __hip_bfloat16 h = __float2bfloat16(f);
    return (unsigned int)*reinterpret_cast<unsigned short*>(&h);
}
// +4 pad dwords every 32: sliding b128 reads conflict-free (R5-validated)
__device__ __forceinline__ int swz(int p) { return p + ((p >> 5) << 2); }

// ---- Setup: banded temporal-B fragments, frag-ordered (R5 band math, validated) ----
// bandB[(f*3+s)*64 + lane] = uint4 of 8 bf16: B_s[k=8q+j][n] = cw[32s+k-n] (0 outside [0,64))
__global__ void k_band(const float* __restrict__ cw, uint4* __restrict__ bandB) {
    const int f = blockIdx.x, l = threadIdx.x;
    const int n = l & 15, q = l >> 4;
    for (int s = 0; s < 3; ++s) {
        FragU o;
#pragma unroll
        for (int i = 0; i < 4; ++i) {
            int i0 = 32 * s + 8 * q + 2 * i - n;
            int i1 = i0 + 1;
            float a = (i0 >= 0 && i0 < KS) ? cw[(size_t)f * KS + i0] : 0.f;
            float c = (i1 >= 0 && i1 < KS) ? cw[(size_t)f * KS + i1] : 0.f;
            o.u[i] = f2bf_u(a) | (f2bf_u(c) << 16);
        }
        bandB[((size_t)f * 3 + s) * 64 + l] = o.q4;
    }
}

// ---- Fused: x -> (spatial MFMA) y in LDS -> (banded MFMA) cos-sim -> out ----
__global__ __launch_bounds__(256, 1) void k_fused(
    const float* __restrict__ x, const float* __restrict__ sw,
    const float* __restrict__ cw, const uint4* __restrict__ bandB,
    const float* __restrict__ weight, const float* __restrict__ bias,
    float* __restrict__ out)
{
    __shared__ unsigned int xTd[RT * SXT];       // 12432 dw: x as bf16 c-pairs, t-rows
    __shared__ unsigned int ych[4][16 * YSTR];   // 14080 dw: per-wave y chunk (bf16)
    __shared__ float sqf[RT];
    __shared__ float rinvD[256];                 // rinv in MFMA D-order
    __shared__ float wnl[FF];
    __shared__ float wred[4];
    const int tid = threadIdx.x;
    const int ln = tid & 63, w = tid >> 6;
    const int m = ln & 15, q = ln >> 4;
    const int b = blockIdx.y;
    const int t0 = blockIdx.x * TTF;
    const int fbase = 32 * w;
    float* sqA = (float*)&ych[0][0];   // 1024 fl (dead before ych writes)
    float* sqB = sqA + 1024;           // 2560 fl

    // ---- phase 0a: stage x t-local [0,256) (R4 pattern) + sq partials ----
    {
        const int tj = tid & 63, cg = tid >> 6;
        float4 s4 = {0.f, 0.f, 0.f, 0.f};
#pragma unroll
        for (int i = 0; i < 8; ++i) {
            int cp = cg * 8 + i;
            const float* xr = x + ((size_t)b * CINN + 2 * cp) * TS + t0 + 4 * tj;
            float4 v0 = *(const float4*)xr;
            float4 v1 = *(const float4*)(xr + TS);
            s4.x += v0.x * v0.x + v1.x * v1.x;
            s4.y += v0.y * v0.y + v1.y * v1.y;
            s4.z += v0.z * v0.z + v1.z * v1.z;
            s4.w += v0.w * v0.w + v1.w * v1.w;
            xTd[(4 * tj + 0) * SXT + cp] = f2bf_u(v0.x) | (f2bf_u(v1.x) << 16);
            xTd[(4 * tj + 1) * SXT + cp] = f2bf_u(v0.y) | (f2bf_u(v1.y) << 16);
            xTd[(4 * tj + 2) * SXT + cp] = f2bf_u(v0.z) | (f2bf_u(v1.z) << 16);
            xTd[(4 * tj + 3) * SXT + cp] = f2bf_u(v0.w) | (f2bf_u(v1.w) << 16);
        }
        *(float4*)(sqA + cg * 256 + 4 * tj) = s4;
    }
    // ---- phase 0b: stage halo t-local [256,336): 640 units = 20 quads x 32 cpairs ----
    for (int u = tid; u < 640; u += 256) {
        int quad = u >> 5, cp = u & 31;
        int tl = 256 + 4 * quad;
        int gt = t0 + tl; if (gt > TS - 4) gt = TS - 4;   // clamp: finite garbage, masked
        const float* xr = x + ((size_t)b * CINN + 2 * cp) * TS + gt;
        float4 v0 = *(const float4*)xr;
        float4 v1 = *(const float4*)(xr + TS);
        xTd[(tl + 0) * SXT + cp] = f2bf_u(v0.x) | (f2bf_u(v1.x) << 16);
        xTd[(tl + 1) * SXT + cp] = f2bf_u(v0.y) | (f2bf_u(v1.y) << 16);
        xTd[(tl + 2) * SXT + cp] = f2bf_u(v0.z) | (f2bf_u(v1.z) << 16);
        xTd[(tl + 3) * SXT + cp] = f2bf_u(v0.w) | (f2bf_u(v1.w) << 16);
        float4 s4;
        s4.x = v0.x * v0.x + v1.x * v1.x;
        s4.y = v0.y * v0.y + v1.y * v1.y;
        s4.z = v0.z * v0.z + v1.z * v1.z;
        s4.w = v0.w * v0.w + v1.w * v1.w;
        *(float4*)(sqB + cp * 80 + 4 * quad) = s4;
    }
    // ---- phase 0c: per-filter weight norms ----
    if (tid < FF) {
        float ssw = 0.f, scw = 0.f;
#pragma unroll
        for (int i = 0; i < 16; ++i) {
            float4 v = *(const float4*)(sw + (size_t)tid * CINN + 4 * i);
            ssw += v.x * v.x + v.y * v.y + v.z * v.z + v.w * v.w;
            float4 c = *(const float4*)(cw + (size_t)tid * KS + 4 * i);
            scw += c.x * c.x + c.y * c.y + c.z * c.z + c.w * c.w;
        }
        wnl[tid] = weight[tid] * rsqrtf(ssw * scw) * (64.0f / (float)TOUT);
    }
    // ---- phase 0d: spatial A-fragments (sw, R4-validated layout) ----
    short8 Afr[2][2];
#pragma unroll
    for (int c = 0; c < 2; ++c)
#pragma unroll
        for (int s = 0; s < 2; ++s) {
            const float* swr = sw + (size_t)(fbase + 16 * c + m) * CINN + s * 32 + q * 8;
            float4 w0 = *(const float4*)swr;
            float4 w1 = *(const float4*)(swr + 4);
            FragU fa;
            fa.u[0] = f2bf_u(w0.x) | (f2bf_u(w0.y) << 16);
            fa.u[1] = f2bf_u(w0.z) | (f2bf_u(w0.w) << 16);
            fa.u[2] = f2bf_u(w1.x) | (f2bf_u(w1.y) << 16);
            fa.u[3] = f2bf_u(w1.z) | (f2bf_u(w1.w) << 16);
            Afr[c][s] = fa.v;
        }
    __syncthreads();   // B1: xTd, sqA/sqB, wnl visible

    // ---- phase 1: reduce sq partials -> sqf[336] ----
    if (tid < 64) {
        float4 a0 = *(const float4*)(sqA + 4 * tid);
        float4 a1 = *(const float4*)(sqA + 256 + 4 * tid);
        float4 a2 = *(const float4*)(sqA + 512 + 4 * tid);
        float4 a3 = *(const float4*)(sqA + 768 + 4 * tid);
        float4 s; s.x = a0.x + a1.x + a2.x + a3.x; s.y = a0.y + a1.y + a2.y + a3.y;
        s.z = a0.z + a1.z + a2.z + a3.z; s.w = a0.w + a1.w + a2.w + a3.w;
        *(float4*)(sqf + 4 * tid) = s;
    } else if (tid < 144) {
        int t = tid - 64;   // [0,80)
        float s = 0.f;
        for (int cp = 0; cp < 32; ++cp) s += sqB[cp * 80 + t];
        sqf[256 + t] = s;
    }
    __syncthreads();   // B2: sqf visible; sqA/sqB dead -> ych usable

    // ---- phase 2: rinv sliding window -> rinvD (D-order; R5-validated scatter) ----
    if (tid < 32) {
        const int base = 8 * tid;
        float s = 0.f;
        for (int k = 0; k < KS; ++k) s += sqf[base + k];
#pragma unroll
        for (int j = 0; j < 8; ++j) {
            int tl = base + j;
            float rv = (t0 + tl < TOUT) ? rsqrtf(s) : 0.f;
            int nn = tl & 15, mr = tl >> 4;
            rinvD[((mr >> 2) * 16 + nn) * 4 + (mr & 3)] = rv;
            s += sqf[tl + KS] - sqf[tl];
        }
    }

    // ---- phase 3: per-wave chunks: spatial MFMA -> ych -> temporal banded MFMA ----
    float acc = 0.f;
    unsigned short* yrow = (unsigned short*)&ych[w][0];
    for (int c = 0; c < 2; ++c) {
        // spatial: f-tile [fbase+16c, +16) x t [0,336) -> ych bf16
#pragma unroll
        for (int tt = 0; tt < 21; ++tt) {
            const int ad = m * SXT + tt * (16 * SXT) + q * 4;
            FragU b0, b1;
#pragma unroll
            for (int i = 0; i < 4; ++i) { b0.u[i] = xTd[ad + i]; b1.u[i] = xTd[ad + 16 + i]; }
            f32x4 d = {0.f, 0.f, 0.f, 0.f};
            d = __builtin_amdgcn_mfma_f32_16x16x32_bf16(Afr[c][0], b0.v, d, 0, 0, 0);
            d = __builtin_amdgcn_mfma_f32_16x16x32_bf16(Afr[c][1], b1.v, d, 0, 0, 0);
            // lane holds y[f-local=4q+r][t=16tt+m] -> bf16 halfword store
            const int inner = swz(8 * tt + (m >> 1));
#pragma unroll
            for (int r = 0; r < 4; ++r)
                yrow[2 * ((4 * q + r) * YSTR + inner) + (m & 1)] =
                    (unsigned short)f2bf_u(d[r]);
        }
        __syncthreads();   // ych chunk complete (also publishes rinvD on c==0)

        float4 r4 = *(const float4*)(rinvD + 4 * ln);
        float rr[4]; *(float4*)rr = r4;

        // temporal: 16 filters, register-dbuf'd band + A fragments
        const int fc = fbase + 16 * c;
        FragU fb0, fb1, fb2, a0, a1, a2;
        fb0.q4 = bandB[((size_t)fc * 3 + 0) * 64 + ln];
        fb1.q4 = bandB[((size_t)fc * 3 + 1) * 64 + ln];
        fb2.q4 = bandB[((size_t)fc * 3 + 2) * 64 + ln];
        a0.q4 = *(const uint4*)&ych[w][0 * YSTR + swz(8 * m + 0 + 4 * q)];
        a1.q4 = *(const uint4*)&ych[w][0 * YSTR + swz(8 * m + 16 + 4 * q)];
        a2.q4 = *(const uint4*)&ych[w][0 * YSTR + swz(8 * m + 32 + 4 * q)];
        for (int fi = 0; fi < 16; ++fi) {
            FragU nb0, nb1, nb2, na0, na1, na2;
            if (fi < 15) {
                const int fn = fc + fi + 1;
                nb0.q4 = bandB[((size_t)fn * 3 + 0) * 64 + ln];
                nb1.q4 = bandB[((size_t)fn * 3 + 1) * 64 + ln];
                nb2.q4 = bandB[((size_t)fn * 3 + 2) * 64 + ln];
                na0.q4 = *(const uint4*)&ych[w][(fi + 1) * YSTR + swz(8 * m + 0 + 4 * q)];
                na1.q4 = *(const uint4*)&ych[w][(fi + 1) * YSTR + swz(8 * m + 16 + 4 * q)];
                na2.q4 = *(const uint4*)&ych[w][(fi + 1) * YSTR + swz(8 * m + 32 + 4 * q)];
            }
            f32x4 d = {0.f, 0.f, 0.f, 0.f};
            d = __builtin_amdgcn_mfma_f32_16x16x32_bf16(a0.v, fb0.v, d, 0, 0, 0);
            d = __builtin_amdgcn_mfma_f32_16x16x32_bf16(a1.v, fb1.v, d, 0, 0, 0);
            d = __builtin_amdgcn_mfma_f32_16x16x32_bf16(a2.v, fb2.v, d, 0, 0, 0);
            float fs = fabsf(d[0]) * rr[0] + fabsf(d[1]) * rr[1]
                     + fabsf(d[2]) * rr[2] + fabsf(d[3]) * rr[3];
            acc += wnl[fc + fi] * fs;
            fb0 = nb0; fb1 = nb1; fb2 = nb2; a0 = na0; a1 = na1; a2 = na2;
        }
        __syncthreads();   // WAR: chunk reads done before next chunk's writes
    }

    // ---- block reduction + atomic ----
    for (int off = 32; off > 0; off >>= 1) acc += __shfl_down(acc, off, 64);
    if (ln == 0) wred[w] = acc;
    __syncthreads();
    if (tid == 0) atomicAdd(out + b, wred[0] + wred[1] + wred[2] + wred[3]);
    if (blockIdx.x == 0 && tid < FF) {
        float v = bias[tid];
        for (int off = 32; off > 0; off >>= 1) v += __shfl_down(v, off, 64);
        if ((tid & 63) == 0) atomicAdd(out + b, v);
    }
}

// --------- Fallback (no workspace): one block per (f,b), LDS rows ----------
__global__ __launch_bounds__(256) void k_naive(
    const float* __restrict__ x, const float* __restrict__ cw,
    const float* __restrict__ sw, const float* __restrict__ weight,
    const float* __restrict__ bias, float* __restrict__ out)
{
    __shared__ float yl[TS];
    __shared__ float ql[TS];
    __shared__ float wred[4];
    const int f = blockIdx.x, b = blockIdx.y, tid = threadIdx.x;
    for (int t = tid; t < TS; t += 256) {
        float a = 0.f, s = 0.f;
        for (int c = 0; c < CINN; ++c) {
            float v = x[((size_t)b * CINN + c) * TS + t];
            a += sw[(size_t)f * CINN + c] * v;
            s += v * v;
        }
        yl[t] = a; ql[t] = s;
    }
    __syncthreads();
    float acc = 0.f;
    for (int t = tid; t < TOUT; t += 256) {
        float cv = 0.f, sl = 0.f;
        for (int k = 0; k < KS; ++k) { cv += cw[(size_t)f * KS + k] * yl[t + k]; sl += ql[t + k]; }
        acc += fabsf(cv) * rsqrtf(sl);
    }
    float ssw = 0.f, scw = 0.f;
    for (int c = 0; c < CINN; ++c) { float v = sw[(size_t)f * CINN + c]; ssw += v * v; }
    for (int k = 0; k < KS; ++k)   { float v = cw[(size_t)f * KS + k];  scw += v * v; }
    const float wnf = weight[f] * rsqrtf(ssw * scw) * 64.0f / (float)TOUT;
    for (int off = 32; off > 0; off >>= 1) acc += __shfl_down(acc, off, 64);
    if ((tid & 63) == 0) wred[tid >> 6] = acc;
    __syncthreads();
    if (tid == 0) {
        float tot = (wred[0] + wred[1] + wred[2] + wred[3]) * wnf;
        if (f == 0) {
            float bsum = 0.f;
            for (int ff = 0; ff < FF; ++ff) bsum += bias[ff];
            tot += bsum;
        }
        atomicAdd(out + b, tot);
    }
}

extern "C" void kernel_launch(void* const* d_in, const int* in_sizes, int n_in,
                              void* d_out, int out_size, void* d_ws, size_t ws_size,
                              hipStream_t stream) {
    const float* x  = (const float*)d_in[0];
    const float* cw = (const float*)d_in[1];   // [F,K]
    const float* sw = (const float*)d_in[2];   // [F,CIN]
    const float* w  = (const float*)d_in[3];   // [F]
    const float* bs = (const float*)d_in[4];   // [F]
    float* out = (float*)d_out;

    hipMemsetAsync(d_out, 0, (size_t)out_size * sizeof(float), stream);

    const size_t bandBytes = (size_t)FF * 3 * 64 * 16;   // 384 KB
    if (ws_size >= bandBytes) {
        uint4* bandB = (uint4*)d_ws;
        k_band <<<dim3(FF), 64, 0, stream>>>(cw, bandB);
        k_fused<<<dim3(TS / TTF, BB), 256, 0, stream>>>(x, sw, cw, bandB, w, bs, out);
    } else {
        k_naive<<<dim3(FF, BB), 256, 0, stream>>>(x, cw, sw, w, bs, out);
    }
}

// Round 9
// 143.535 us; speedup vs baseline: 1.0738x; 1.0738x over previous
//
#include <hip/hip_runtime.h>
#include <hip/hip_bf16.h>
#include <cstdint>
#include <cstddef>

#define BB   64
#define CINN 64
#define TS   4096
#define FF   128
#define KS   64
#define TOUT (TS - KS + 1)   // 4033
#define TT   2048            // outputs per k_temporal block (8 tiles of 256)
#define FGZ  8               // filters per k_temporal block
#define SEG  (TT + KS)       // 2112 sq values staged for rinv

// k_spatial_mfma tiling (R4-validated)
#define TPB   256
#define SXT   37
#define SYB   68

typedef __attribute__((ext_vector_type(8))) short short8;
typedef __attribute__((ext_vector_type(4))) float f32x4;
union FragU { unsigned int u[4]; short8 v; uint4 q4; };

static __device__ __forceinline__ unsigned int f2bf_u(float f) {
    __hip_bfloat16 h = __float2bfloat16(f);
    return (unsigned int)*reinterpret_cast<unsigned short*>(&h);
}

// ---- Setup: banded temporal-B fragments (R5/R6-validated) + fused norm weights ----
// bandB[(f*3+s)*64 + lane] = 8 bf16: B_s[k=8q+j][n] = cw[32s+k-n] (0 outside [0,64))
__global__ void k_band(const float* __restrict__ cw, const float* __restrict__ sw,
                       const float* __restrict__ weight,
                       uint4* __restrict__ bandB, float* __restrict__ wnf) {
    const int f = blockIdx.x, l = threadIdx.x;
    const int n = l & 15, q = l >> 4;
    for (int s = 0; s < 3; ++s) {
        FragU o;
#pragma unroll
        for (int i = 0; i < 4; ++i) {
            int i0 = 32 * s + 8 * q + 2 * i - n;
            int i1 = i0 + 1;
            float a = (i0 >= 0 && i0 < KS) ? cw[(size_t)f * KS + i0] : 0.f;
            float c = (i1 >= 0 && i1 < KS) ? cw[(size_t)f * KS + i1] : 0.f;
            o.u[i] = f2bf_u(a) | (f2bf_u(c) << 16);
        }
        bandB[((size_t)f * 3 + s) * 64 + l] = o.q4;
    }
    // per-filter weight * rsqrt(|sw_f|^2 * |cw_f|^2) * scale / TOUT
    float a = sw[(size_t)f * CINN + l], c = cw[(size_t)f * KS + l];
    float v = a * a, u = c * c;
    for (int off = 32; off > 0; off >>= 1) {
        v += __shfl_down(v, off, 64);
        u += __shfl_down(u, off, 64);
    }
    if (l == 0) wnf[f] = weight[f] * rsqrtf(v * u) * (64.0f / (float)TOUT);
}

// ============ Kernel 1: spatial GEMM via MFMA (bf16), + sq  [R4, unchanged] ============
__global__ __launch_bounds__(256) void k_spatial_mfma(
    const float* __restrict__ x, const float* __restrict__ sw,
    __hip_bfloat16* __restrict__ y, float* __restrict__ sq)
{
    __shared__ unsigned int xTd[TPB * SXT];
    __shared__ float ybuf[4 * 32 * SYB];
    __shared__ float sqred[4 * TPB];
    const int tid = threadIdx.x;
    const int b = blockIdx.y;
    const int t0 = blockIdx.x * TPB;

    {
        const int tj = tid & 63;
        const int cg = tid >> 6;
        float4 s4 = {0.f, 0.f, 0.f, 0.f};
#pragma unroll
        for (int i = 0; i < 8; ++i) {
            int cp = cg * 8 + i;
            const float* xr = x + ((size_t)b * CINN + 2 * cp) * TS + t0 + 4 * tj;
            float4 v0 = *(const float4*)xr;
            float4 v1 = *(const float4*)(xr + TS);
            s4.x += v0.x * v0.x + v1.x * v1.x;
            s4.y += v0.y * v0.y + v1.y * v1.y;
            s4.z += v0.z * v0.z + v1.z * v1.z;
            s4.w += v0.w * v0.w + v1.w * v1.w;
            xTd[(4 * tj + 0) * SXT + cp] = f2bf_u(v0.x) | (f2bf_u(v1.x) << 16);
            xTd[(4 * tj + 1) * SXT + cp] = f2bf_u(v0.y) | (f2bf_u(v1.y) << 16);
            xTd[(4 * tj + 2) * SXT + cp] = f2bf_u(v0.z) | (f2bf_u(v1.z) << 16);
            xTd[(4 * tj + 3) * SXT + cp] = f2bf_u(v0.w) | (f2bf_u(v1.w) << 16);
        }
        *(float4*)(sqred + cg * TPB + 4 * tj) = s4;
    }
    __syncthreads();
    if (tid < 64) {
        float4 a0 = *(const float4*)(sqred + 4 * tid);
        float4 a1 = *(const float4*)(sqred + TPB + 4 * tid);
        float4 a2 = *(const float4*)(sqred + 2 * TPB + 4 * tid);
        float4 a3 = *(const float4*)(sqred + 3 * TPB + 4 * tid);
        float4 s; s.x = a0.x + a1.x + a2.x + a3.x; s.y = a0.y + a1.y + a2.y + a3.y;
        s.z = a0.z + a1.z + a2.z + a3.z; s.w = a0.w + a1.w + a2.w + a3.w;
        *(float4*)(sq + (size_t)b * TS + t0 + 4 * tid) = s;
    }

    const int w  = tid >> 6;
    const int ln = tid & 63;
    const int m  = ln & 15;
    const int q  = ln >> 4;
    const int fbase = 32 * w;

    short8 Afr[2][2];
#pragma unroll
    for (int p = 0; p < 2; ++p)
#pragma unroll
        for (int s = 0; s < 2; ++s) {
            const float* swr = sw + (size_t)(fbase + 16 * p + m) * CINN + s * 32 + q * 8;
            float4 w0 = *(const float4*)swr;
            float4 w1 = *(const float4*)(swr + 4);
            FragU fa;
            fa.u[0] = f2bf_u(w0.x) | (f2bf_u(w0.y) << 16);
            fa.u[1] = f2bf_u(w0.z) | (f2bf_u(w0.w) << 16);
            fa.u[2] = f2bf_u(w1.x) | (f2bf_u(w1.y) << 16);
            fa.u[3] = f2bf_u(w1.z) | (f2bf_u(w1.w) << 16);
            Afr[p][s] = fa.v;
        }

    const int baseB = m * SXT + q * 4;
    float* yb = ybuf + w * (32 * SYB);

#pragma unroll
    for (int strip = 0; strip < 4; ++strip) {
#pragma unroll
        for (int tti = 0; tti < 4; ++tti) {
            const int tt = strip * 4 + tti;
            const int ad = baseB + tt * (16 * SXT);
            FragU b0, b1;
#pragma unroll
            for (int i = 0; i < 4; ++i) { b0.u[i] = xTd[ad + i]; b1.u[i] = xTd[ad + 16 + i]; }
            f32x4 acc0 = {0.f, 0.f, 0.f, 0.f};
            f32x4 acc1 = {0.f, 0.f, 0.f, 0.f};
            acc0 = __builtin_amdgcn_mfma_f32_16x16x32_bf16(Afr[0][0], b0.v, acc0, 0, 0, 0);
            acc0 = __builtin_amdgcn_mfma_f32_16x16x32_bf16(Afr[0][1], b1.v, acc0, 0, 0, 0);
            acc1 = __builtin_amdgcn_mfma_f32_16x16x32_bf16(Afr[1][0], b0.v, acc1, 0, 0, 0);
            acc1 = __builtin_amdgcn_mfma_f32_16x16x32_bf16(Afr[1][1], b1.v, acc1, 0, 0, 0);
            const int tl = tti * 16 + m;
#pragma unroll
            for (int r = 0; r < 4; ++r) {
                yb[(4 * q + r) * SYB + tl]      = acc0[r];
                yb[(16 + 4 * q + r) * SYB + tl] = acc1[r];
            }
        }
#pragma unroll
        for (int pr = 0; pr < 8; ++pr) {
            const int fl = pr * 4 + q;
            float4 v = *(const float4*)(yb + fl * SYB + 4 * m);
            uint2 o;
            o.x = f2bf_u(v.x) | (f2bf_u(v.y) << 16);
            o.y = f2bf_u(v.z) | (f2bf_u(v.w) << 16);
            *(uint2*)(y + ((size_t)b * FF + fbase + fl) * TS + t0 + strip * 64 + 4 * m) = o;
        }
    }
}

// ============ Kernel 2: temporal banded MFMA, A-fragments DIRECT from global ============
// out[t0+16m+n] = sum_s A_s[m][k]·B_s[k][n]; A lane load = y[t0+tile*256+16m+32s+8q .. +8)
// Reads may overrun a row by <=160 B: interior rows land in the next filter row
// (finite bf16 x band-zero = 0); the LAST row lands in the zeroed guard region
// (R7 post-mortem: unguarded overrun hit sq floats whose bytes can decode as
// bf16 Inf/NaN -> 0*Inf = NaN poisoned valid outputs).
__global__ __launch_bounds__(256) void k_temporal_direct(
    const __hip_bfloat16* __restrict__ y, const float* __restrict__ sq,
    const uint4* __restrict__ bandB, const float* __restrict__ wnf,
    const float* __restrict__ bias, float* __restrict__ out)
{
    __shared__ float rbuf[SEG];   // sq stage -> (after barrier) rinv in D-order
    __shared__ float wred[4];
    const int tid = threadIdx.x;
    const int ln = tid & 63, w = tid >> 6;
    const int m = ln & 15, q = ln >> 4;
    const int b = blockIdx.y;
    const int t0 = blockIdx.x * TT;
    const int f0 = blockIdx.z * FGZ;

    // ---- stage sq segment (R5-validated clamp/mask scheme) ----
    const float* sqrow = sq + (size_t)b * TS;
#pragma unroll
    for (int it = 0; it < 3; ++it) {
        int j = tid + 256 * it;            // float4 index, SEG/4 = 528
        if (j < SEG / 4) {
            int p = t0 + 4 * j; if (p > TS - 4) p = TS - 4;
            *(float4*)(rbuf + 4 * j) = *(const float4*)(sqrow + p);
        }
    }
    __syncthreads();

    // ---- rinv per thread (8 t's) ----
    const int base = 8 * tid;
    float rv[8];
    {
        float hd[8], tl[8];
        float s = 0.f;
#pragma unroll
        for (int mm = 0; mm < 16; ++mm) {
            float4 v = *(const float4*)(rbuf + base + 4 * mm);
            if (mm < 2) { hd[4 * mm] = v.x; hd[4 * mm + 1] = v.y; hd[4 * mm + 2] = v.z; hd[4 * mm + 3] = v.w; }
            s += (v.x + v.y) + (v.z + v.w);
        }
        float4 ta = *(const float4*)(rbuf + base + 64);
        float4 tb = *(const float4*)(rbuf + base + 68);
        tl[0] = ta.x; tl[1] = ta.y; tl[2] = ta.z; tl[3] = ta.w;
        tl[4] = tb.x; tl[5] = tb.y; tl[6] = tb.z; tl[7] = tb.w;
#pragma unroll
        for (int j = 0; j < 8; ++j) {
            int tpos = t0 + base + j;
            rv[j] = (tpos < TOUT) ? rsqrtf(s) : 0.f;   // masks tail outputs
            s += tl[j] - hd[j];
        }
    }
    __syncthreads();
    // scatter rinv into D-order (R5-validated): t-local -> tile*256 + (q*16+n)*4 + r
#pragma unroll
    for (int j = 0; j < 8; ++j) {
        int tl = base + j;
        int nn = tl & 15, mr = (tl >> 4) & 15, tile = tl >> 8;
        rbuf[tile * 256 + ((mr >> 2) * 16 + nn) * 4 + (mr & 3)] = rv[j];
    }
    __syncthreads();

    // ---- main loop: 8 filters x 2 tiles/wave, no barriers ----
    const __hip_bfloat16* ybase = y + ((size_t)b * FF + f0) * TS + t0 + 16 * m + 8 * q;
    float acc = 0.f;
    for (int fi = 0; fi < FGZ; ++fi) {
        const uint4* bb = bandB + (size_t)(f0 + fi) * 3 * 64;
        FragU B0, B1, B2;
        B0.q4 = bb[ln]; B1.q4 = bb[64 + ln]; B2.q4 = bb[128 + ln];
        const __hip_bfloat16* yr = ybase + (size_t)fi * TS;
        float facc = 0.f;
#pragma unroll
        for (int ti = 0; ti < 2; ++ti) {
            const int tile = 2 * w + ti;
            FragU a0, a1, a2;
            a0.q4 = *(const uint4*)(yr + tile * 256);
            a1.q4 = *(const uint4*)(yr + tile * 256 + 32);
            a2.q4 = *(const uint4*)(yr + tile * 256 + 64);
            f32x4 d = {0.f, 0.f, 0.f, 0.f};
            d = __builtin_amdgcn_mfma_f32_16x16x32_bf16(a0.v, B0.v, d, 0, 0, 0);
            d = __builtin_amdgcn_mfma_f32_16x16x32_bf16(a1.v, B1.v, d, 0, 0, 0);
            d = __builtin_amdgcn_mfma_f32_16x16x32_bf16(a2.v, B2.v, d, 0, 0, 0);
            float4 r4 = *(const float4*)(rbuf + tile * 256 + 4 * ln);
            float rr[4]; *(float4*)rr = r4;
#pragma unroll
            for (int r = 0; r < 4; ++r) facc += fabsf(d[r]) * rr[r];
        }
        acc += wnf[f0 + fi] * facc;
    }

    // ---- block reduction + atomic ----
    for (int off = 32; off > 0; off >>= 1) acc += __shfl_down(acc, off, 64);
    if (ln == 0) wred[w] = acc;
    __syncthreads();
    if (tid == 0) atomicAdd(out + b, wred[0] + wred[1] + wred[2] + wred[3]);
    if (blockIdx.x == 0 && blockIdx.z == 0 && tid < FF) {
        float v = bias[tid];
        for (int off = 32; off > 0; off >>= 1) v += __shfl_down(v, off, 64);
        if ((tid & 63) == 0) atomicAdd(out + b, v);
    }
}

// --------- Fallback (no workspace): one block per (f,b), LDS rows ----------
__global__ __launch_bounds__(256) void k_naive(
    const float* __restrict__ x, const float* __restrict__ cw,
    const float* __restrict__ sw, const float* __restrict__ weight,
    const float* __restrict__ bias, float* __restrict__ out)
{
    __shared__ float yl[TS];
    __shared__ float ql[TS];
    __shared__ float wred[4];
    const int f = blockIdx.x, b = blockIdx.y, tid = threadIdx.x;
    for (int t = tid; t < TS; t += 256) {
        float a = 0.f, s = 0.f;
        for (int c = 0; c < CINN; ++c) {
            float v = x[((size_t)b * CINN + c) * TS + t];
            a += sw[(size_t)f * CINN + c] * v;
            s += v * v;
        }
        yl[t] = a; ql[t] = s;
    }
    __syncthreads();
    float acc = 0.f;
    for (int t = tid; t < TOUT; t += 256) {
        float cv = 0.f, sl = 0.f;
        for (int k = 0; k < KS; ++k) { cv += cw[(size_t)f * KS + k] * yl[t + k]; sl += ql[t + k]; }
        acc += fabsf(cv) * rsqrtf(sl);
    }
    float ssw = 0.f, scw = 0.f;
    for (int c = 0; c < CINN; ++c) { float v = sw[(size_t)f * CINN + c]; ssw += v * v; }
    for (int k = 0; k < KS; ++k)   { float v = cw[(size_t)f * KS + k];  scw += v * v; }
    const float wnf = weight[f] * rsqrtf(ssw * scw) * 64.0f / (float)TOUT;
    for (int off = 32; off > 0; off >>= 1) acc += __shfl_down(acc, off, 64);
    if ((tid & 63) == 0) wred[tid >> 6] = acc;
    __syncthreads();
    if (tid == 0) {
        float tot = (wred[0] + wred[1] + wred[2] + wred[3]) * wnf;
        if (f == 0) {
            float bsum = 0.f;
            for (int ff = 0; ff < FF; ++ff) bsum += bias[ff];
            tot += bsum;
        }
        atomicAdd(out + b, tot);
    }
}

extern "C" void kernel_launch(void* const* d_in, const int* in_sizes, int n_in,
                              void* d_out, int out_size, void* d_ws, size_t ws_size,
                              hipStream_t stream) {
    const float* x  = (const float*)d_in[0];
    const float* cw = (const float*)d_in[1];   // [F,K]
    const float* sw = (const float*)d_in[2];   // [F,CIN]
    const float* w  = (const float*)d_in[3];   // [F]
    const float* bs = (const float*)d_in[4];   // [F]
    float* out = (float*)d_out;

    hipMemsetAsync(d_out, 0, (size_t)out_size * sizeof(float), stream);

    const size_t yBytes    = (size_t)BB * FF * TS * sizeof(__hip_bfloat16); // 67 MB
    const size_t padBytes  = 4096;                                          // zeroed guard after y
    const size_t sqBytes   = (size_t)BB * TS * sizeof(float);               // 1 MB
    const size_t bandBytes = (size_t)FF * 3 * 64 * 16;                      // 384 KB
    const size_t wnBytes   = (size_t)FF * sizeof(float);

    if (yBytes + padBytes + sqBytes + bandBytes + wnBytes <= ws_size) {
        __hip_bfloat16* ybf = (__hip_bfloat16*)d_ws;
        char* p = (char*)d_ws + yBytes;
        // zero the guard so last-row overrun reads are bf16 zeros (graph-capture-safe)
        hipMemsetAsync(p, 0, padBytes, stream);
        float* sq    = (float*)(p + padBytes);
        uint4* bandB = (uint4*)(p + padBytes + sqBytes);
        float* wnf   = (float*)(p + padBytes + sqBytes + bandBytes);
        k_band<<<dim3(FF), 64, 0, stream>>>(cw, sw, w, bandB, wnf);
        k_spatial_mfma  <<<dim3(TS / TPB, BB), 256, 0, stream>>>(x, sw, ybf, sq);
        k_temporal_direct<<<dim3(TS / TT, BB, FF / FGZ), 256, 0, stream>>>(ybf, sq, bandB, wnf, bs, out);
    } else {
        k_naive<<<dim3(FF, BB), 256, 0, stream>>>(x, cw, sw, w, bs, out);
    }
}